// Round 6
// baseline (6465.491 us; speedup 1.0000x reference)
//
#include <hip/hip_runtime.h>
#include <math.h>

#define T_ 60
#define N_ 16384
#define C_ 5
#define H_ 20
#define G_ 80
#define HC_ 15
#define N0_ 3190
#define E0_ 31900
#define K_ 5

// workspace layout (float offsets)
#define OFF_SEQ   0
#define OFF_XH    (T_*N_*H_)            // 19,660,800
#define OFF_XHN   (OFF_XH + N_*H_)
#define OFF_NX0   (OFF_XHN + N_)
#define OFF_RX0   (OFF_NX0 + N0_)
#define OFF_TOP5  (OFF_RX0 + N0_)       // int[ N_*K_ ]
#define OFF_SUM1  (OFF_TOP5 + N_*K_)
#define OFF_CNT1  (OFF_SUM1 + N0_*H_)
#define OFF_OBASE (OFF_CNT1 + N0_)

__device__ __forceinline__ float sigf(float x) {
  return __fdividef(1.0f, 1.0f + __expf(-x));
}
__device__ __forceinline__ float tanhf_fast(float x) {
  float xc = fminf(fmaxf(x, -44.0f), 44.0f);
  float e = __expf(2.0f * xc);
  return __fdividef(e - 1.0f, e + 1.0f);
}

// ============================================================================
// LSTM layer "v16": 16 threads/element -> 4096 waves (3-4 waves/SIMD) with
// DENSE global I/O (r8's 8-sparse-lane 80B-stride access caused ~10x HBM
// amplification: FETCH 2.8GB vs 80MB useful -> memory-bound 3.1TB/s).
//  - lane = slot*16 + rr; rr = q*4 + b owns rows 5rr..5rr+4 of the stacked
//    [80 x 40] [Wih|Whh]: all 5 rows are gate q, units 5b+j. 200 fmac/step.
//  - activation BEFORE gather (halves transcendentals); 20 ds_bpermute
//    exchange activated gates; h-feedback kept in PART order
//    hp[5d+j] = h_nat[5(b^d)+j] via 3x5 shfl_xor(1/2/3) (quad_perm DPP),
//    Whh columns pre-permuted at LDS-stage time (round-2-verified).
//  - natural h store: lane rr<4's own hn IS h_nat[5rr..] -> hst LDS, then
//    lanes rr<5 do dense 320B-aligned float4 global stores. Same dense
//    pattern for loads via double-buffered xst. All staging intra-wave =>
//    ZERO barriers in the t-loop.
//  - weights LDS row stride 44 floats (16B aligned; worst 2-way bank alias
//    = free). LDS total ~18.9KB -> 4 blocks/CU possible.
// ============================================================================

#define WROW 44

template <bool FIRST>
__global__ void __launch_bounds__(256, 3) lstm_v16_kernel(
    const float* __restrict__ xg,      // [T, N, 5] raw codes (FIRST only)
    const float* __restrict__ embw,    // [5, 20]              (FIRST only)
    const float* __restrict__ Wih,     // [80, 20] this layer
    const float* __restrict__ Whh,     // [80, 20]
    const float* __restrict__ bih,     // [80]
    const float* __restrict__ bhh,     // [80]
    float* __restrict__ seq) {         // in (!FIRST) and out: [T, N, 20]
  __shared__ __align__(16) float wts[80 * WROW];
  __shared__ float bl2[80];
  __shared__ float embl[100];
  __shared__ __align__(16) float xst[2][16][20];
  __shared__ __align__(16) float hst[16][20];
  const int tid = threadIdx.x;

  // ---- stage weights: Wih cols natural, Whh cols part-permuted per row ----
  for (int idx = tid; idx < 80 * WROW; idx += 256) {
    int row = idx / WROW, col = idx % WROW;
    float v = 0.0f;
    if (col < 20) {
      v = Wih[row * 20 + col];
    } else if (col < 40) {
      int d = (col - 20) / 5, m = (col - 20) % 5;
      int br = (row / 5) & 3;
      v = Whh[row * 20 + ((br ^ d) * 5 + m)];
    }
    wts[idx] = v;
  }
  if (tid < 80) bl2[tid] = bih[tid] + bhh[tid];
  if (FIRST && tid < 100) embl[tid] = embw[tid];
  __syncthreads();

  const int lane = tid & 63;
  const int wv = tid >> 6;
  const int slot = lane >> 4;          // 0..3 element within wave
  const int rr = lane & 15;            // row-group
  const int q_g = rr >> 2;             // gate (0=i,1=f,2=g,3=o)
  const int b = rr & 3;                // unit block (units 5b..5b+4)
  const int e_blk = (wv << 2) + slot;  // element within block (0..15)
  const int n = (blockIdx.x << 4) + e_blk;
  const int wbase = rr * 5 * WROW;

  int srcA0, srcA1, srcA2, srcA3;      // bpermute byte addrs: lane slot*16+q*4+b
  srcA0 = ((slot << 4) + 0 + b) << 2;
  srcA1 = ((slot << 4) + 4 + b) << 2;
  srcA2 = ((slot << 4) + 8 + b) << 2;
  srcA3 = ((slot << 4) + 12 + b) << 2;

  float bs[5];
#pragma unroll
  for (int j = 0; j < 5; j++) bs[j] = bl2[rr * 5 + j];

  float hp[20], c[5];
#pragma unroll
  for (int k = 0; k < 20; k++) hp[k] = 0.0f;
#pragma unroll
  for (int j = 0; j < 5; j++) c[j] = 0.0f;

  // ---- initial input (t=0) into xst[0] (loader lanes rr<5, intra-wave) ----
  if (rr < 5) {
    if (FIRST) {
      xst[0][e_blk][rr] = xg[(size_t)n * 5 + rr];
    } else {
      float4 v = *reinterpret_cast<const float4*>(seq + (size_t)n * 20 + rr * 4);
      *reinterpret_cast<float4*>(&xst[0][e_blk][rr * 4]) = v;
    }
  }

  for (int t = 0; t < T_; t++) {
    const int cur = t & 1;
    // prefetch t+1 into regs (dense: 20 lanes/wave, 320B fully-covered span)
    float4 gx; float gf;
    if (rr < 5 && t + 1 < T_) {
      if (FIRST) {
        gf = xg[((size_t)(t + 1) * N_ + n) * 5 + rr];
      } else {
        gx = *reinterpret_cast<const float4*>(seq + ((size_t)(t + 1) * N_ + n) * 20 + rr * 4);
      }
    }
    // read current input from xst (broadcast within slot)
    float x[20];
    if (FIRST) {
      float raw0 = xst[cur][e_blk][0], raw1 = xst[cur][e_blk][1];
      float raw2 = xst[cur][e_blk][2], raw3 = xst[cur][e_blk][3];
      float raw4 = xst[cur][e_blk][4];
#pragma unroll
      for (int k = 0; k < 20; k++) {
        float a = raw0 * embl[k] + raw1 * embl[20 + k] + raw2 * embl[40 + k]
                + raw3 * embl[60 + k] + raw4 * embl[80 + k];
        x[k] = fmaxf(a, 0.f);
      }
    } else {
#pragma unroll
      for (int q = 0; q < 5; q++) {
        float4 v = *reinterpret_cast<const float4*>(&xst[cur][e_blk][q * 4]);
        x[4 * q] = v.x; x[4 * q + 1] = v.y; x[4 * q + 2] = v.z; x[4 * q + 3] = v.w;
      }
    }
    // 5 rows x 40 fmacs
    float av[5];
#pragma unroll
    for (int j = 0; j < 5; j++) {
      const float* wr = &wts[wbase + j * WROW];
      float a = bs[j];
#pragma unroll
      for (int k = 0; k < 20; k++) a += x[k] * wr[k];
#pragma unroll
      for (int k = 0; k < 20; k++) a += hp[k] * wr[20 + k];
      // own-gate activation (gate g uses tanh, others sigmoid)
      float sv = sigf(a);
      float tv = tanhf_fast(a);
      av[j] = (q_g == 2) ? tv : sv;
    }
    // gather activated gates for units 5b+j
    float hn[5];
#pragma unroll
    for (int j = 0; j < 5; j++) {
      int avi = __float_as_int(av[j]);
      float gi = __int_as_float(__builtin_amdgcn_ds_bpermute(srcA0, avi));
      float gf_ = __int_as_float(__builtin_amdgcn_ds_bpermute(srcA1, avi));
      float gg = __int_as_float(__builtin_amdgcn_ds_bpermute(srcA2, avi));
      float go = __int_as_float(__builtin_amdgcn_ds_bpermute(srcA3, avi));
      float cu = gf_ * c[j] + gi * gg;
      c[j] = cu;
      hn[j] = go * tanhf_fast(cu);
    }
    // part-order h feedback (quad_perm shuffles; compile-time positions)
#pragma unroll
    for (int j = 0; j < 5; j++) {
      hp[j] = hn[j];
      hp[5 + j] = __shfl_xor(hn[j], 1, 64);
      hp[10 + j] = __shfl_xor(hn[j], 2, 64);
      hp[15 + j] = __shfl_xor(hn[j], 3, 64);
    }
    // natural-order store via hst (intra-wave)
    if (rr < 4) {
#pragma unroll
      for (int j = 0; j < 5; j++) hst[e_blk][rr * 5 + j] = hn[j];
    }
    if (rr < 5) {
      float4 hv = *reinterpret_cast<const float4*>(&hst[e_blk][rr * 4]);
      *reinterpret_cast<float4*>(seq + ((size_t)t * N_ + n) * 20 + rr * 4) = hv;
      if (t + 1 < T_) {
        if (FIRST) xst[cur ^ 1][e_blk][rr] = gf;
        else *reinterpret_cast<float4*>(&xst[cur ^ 1][e_blk][rr * 4]) = gx;
      }
    }
  }
}

// ---------------- attention over T, one wave per element ----------------
__global__ void __launch_bounds__(256) attn_kernel(
    const float* __restrict__ seq, const float* __restrict__ w1,
    const float* __restrict__ b1v, const float* __restrict__ w2,
    const float* __restrict__ b2v, float* __restrict__ xh, float* __restrict__ xhn) {
  const int wv = threadIdx.x >> 6;
  const int t = threadIdx.x & 63;
  const int n = (blockIdx.x << 2) + wv;
  const bool act = (t < T_);
  float enc[20];
#pragma unroll
  for (int k = 0; k < 20; k++) enc[k] = 0.0f;
  if (act) {
    const float* p = seq + (t * N_ + n) * H_;
#pragma unroll
    for (int q = 0; q < 5; q++) {
      float4 v = *reinterpret_cast<const float4*>(p + 4 * q);
      enc[4 * q] = v.x; enc[4 * q + 1] = v.y; enc[4 * q + 2] = v.z; enc[4 * q + 3] = v.w;
    }
  }
  float e = -3.0e38f;
  if (act) {
    e = b2v[0];
#pragma unroll 4
    for (int k = 0; k < 64; k++) {
      float s = b1v[k];
      const float* wr = w1 + k * 20;
#pragma unroll
      for (int m = 0; m < 20; m++) s += wr[m] * enc[m];
      s = fmaxf(s, 0.0f);
      e += w2[k] * s;
    }
  }
  float mx = e;
#pragma unroll
  for (int d = 32; d; d >>= 1) mx = fmaxf(mx, __shfl_xor(mx, d, 64));
  float p_ = act ? __expf(e - mx) : 0.0f;
  float sm = p_;
#pragma unroll
  for (int d = 32; d; d >>= 1) sm += __shfl_xor(sm, d, 64);
  float w = __fdividef(p_, sm);
  float a[20];
#pragma unroll
  for (int k = 0; k < 20; k++) a[k] = enc[k] * w;
#pragma unroll
  for (int d = 1; d < 64; d <<= 1) {
#pragma unroll
    for (int k = 0; k < 20; k++) a[k] += __shfl_xor(a[k], d, 64);
  }
  if (t == 0) {
    float* op = xh + n * 20;
    float s2 = 0.0f;
#pragma unroll
    for (int k = 0; k < 20; k++) s2 += a[k] * a[k];
#pragma unroll
    for (int q = 0; q < 5; q++) {
      float4 v; v.x = a[4 * q]; v.y = a[4 * q + 1]; v.z = a[4 * q + 2]; v.w = a[4 * q + 3];
      *reinterpret_cast<float4*>(op + 4 * q) = v;
    }
    xhn[n] = sqrtf(s2);
  }
}

// ---------------- x0 norms ----------------
__global__ void __launch_bounds__(256) x0norm_kernel(const float* __restrict__ x0,
                                                     float* __restrict__ nx0,
                                                     float* __restrict__ rx0) {
  int j = blockIdx.x * 256 + threadIdx.x;
  if (j >= N0_) return;
  float s = 0.f;
#pragma unroll
  for (int k = 0; k < 20; k++) { float v = x0[j * 20 + k]; s += v * v; }
  float nv = sqrtf(s);
  nx0[j] = nv;
  rx0[j] = 1.0f / nv;
}

// ---------------- top-6 cosine, 4 lanes per row ----------------
__device__ __forceinline__ bool better_(float v1, int i1, float v2, int i2) {
  return (v1 > v2) || (v1 == v2 && i1 < i2);
}

__device__ __forceinline__ void merge6(float tv[6], int ti[6], int d) {
  float cv[12]; int ci[12];
#pragma unroll
  for (int z = 0; z < 6; z++) { cv[z] = tv[z]; ci[z] = ti[z]; }
#pragma unroll
  for (int z = 0; z < 6; z++) {
    cv[6 + z] = __shfl_xor(tv[z], d, 64);
    ci[6 + z] = __shfl_xor(ti[z], d, 64);
  }
#pragma unroll
  for (int o = 0; o < 6; o++) {
    float bv = -3.0e38f; int bi = 0x7fffffff; int bm = -1;
#pragma unroll
    for (int m = 0; m < 12; m++) {
      bool bt = better_(cv[m], ci[m], bv, bi);
      if (bt) { bv = cv[m]; bi = ci[m]; bm = m; }
    }
    tv[o] = bv; ti[o] = bi;
#pragma unroll
    for (int m = 0; m < 12; m++) if (m == bm) cv[m] = -3.0e38f;
  }
}

__global__ void __launch_bounds__(256) topk_kernel(
    const float* __restrict__ x0, const float* __restrict__ xh,
    const float* __restrict__ xhn, const float* __restrict__ nx0,
    const float* __restrict__ rx0, int* __restrict__ top5) {
  const int gt = blockIdx.x * 256 + threadIdx.x;
  const int i = gt >> 2, sub = gt & 3;
  float q[20];
  const float* qp = xh + i * 20;
#pragma unroll
  for (int z = 0; z < 5; z++) {
    float4 v = *reinterpret_cast<const float4*>(qp + 4 * z);
    q[4 * z] = v.x; q[4 * z + 1] = v.y; q[4 * z + 2] = v.z; q[4 * z + 3] = v.w;
  }
  float tv[6]; int ti[6];
#pragma unroll
  for (int z = 0; z < 6; z++) { tv[z] = -1.0e30f; ti[z] = 0x7fffffff; }
  for (int j = sub; j < N0_; j += 4) {
    const float* xr = x0 + j * 20;
    float d0 = 0.f;
#pragma unroll
    for (int k = 0; k < 20; k++) d0 += q[k] * xr[k];
    float key = d0 * rx0[j];
    if (key > tv[5]) {       // within-lane j ascending => strict > keeps stability
      tv[5] = key; ti[5] = j;
#pragma unroll
      for (int z = 5; z >= 1; z--) {
        bool sw = better_(tv[z], ti[z], tv[z - 1], ti[z - 1]);
        if (sw) {
          float fv = tv[z]; tv[z] = tv[z - 1]; tv[z - 1] = fv;
          int iv = ti[z]; ti[z] = ti[z - 1]; ti[z - 1] = iv;
        }
      }
    }
  }
  merge6(tv, ti, 1);
  merge6(tv, ti, 2);
  if (sub == 0) {
    const float* xr = x0 + ti[0] * 20;
    float d0 = 0.f;
#pragma unroll
    for (int k = 0; k < 20; k++) d0 += q[k] * xr[k];
    float a = (d0 / xhn[i]) / nx0[ti[0]];   // replicate ref's exact-match branch
    int base = (a == 1.0f) ? 1 : 0;
#pragma unroll
    for (int z = 0; z < 5; z++) top5[i * 5 + z] = ti[base + z];
  }
}

// ---------------- SAGE layer-1 aggregation over edge_0 ----------------
__global__ void __launch_bounds__(256) scatter_kernel(const int* __restrict__ edge,
                                                      const float* __restrict__ x0,
                                                      float* sum1, float* cnt1) {
  int e = blockIdx.x * 256 + threadIdx.x;
  if (e >= E0_) return;
  int s = edge[e], d = edge[E0_ + e];
  const float* xr = x0 + s * 20;
  float* dr = sum1 + d * 20;
#pragma unroll
  for (int k = 0; k < 20; k++) atomicAdd(dr + k, xr[k]);
  atomicAdd(cnt1 + d, 1.0f);
}

__global__ void __launch_bounds__(256) base_kernel(
    const float* __restrict__ x0, const float* __restrict__ sum1,
    const float* __restrict__ cnt1, const float* __restrict__ w1l,
    const float* __restrict__ w1r, const float* __restrict__ b1,
    float* __restrict__ obase) {
  int j = blockIdx.x * 256 + threadIdx.x;
  if (j >= N0_) return;
  float cm = fmaxf(cnt1[j], 1.0f);
  float mean[20], xv[20];
#pragma unroll
  for (int k = 0; k < 20; k++) {
    mean[k] = sum1[j * 20 + k] / cm;
    xv[k] = x0[j * 20 + k];
  }
#pragma unroll
  for (int c = 0; c < HC_; c++) {
    float a = b1[c];
#pragma unroll
    for (int k = 0; k < 20; k++) a += mean[k] * w1l[c * 20 + k];
#pragma unroll
    for (int k = 0; k < 20; k++) a += xv[k] * w1r[c * 20 + k];
    obase[j * HC_ + c] = fmaxf(a, 0.0f);
  }
}

// ---------------- SAGE layer-2 at new nodes + linear + softmax ----------------
__global__ void __launch_bounds__(256) final_kernel(
    const float* __restrict__ xh, const int* __restrict__ top5,
    const float* __restrict__ obase, const float* __restrict__ w1r,
    const float* __restrict__ b1, const float* __restrict__ w2l,
    const float* __restrict__ w2r, const float* __restrict__ b2,
    const float* __restrict__ wlin, const float* __restrict__ blin,
    float* __restrict__ out) {
  int n = blockIdx.x * 256 + threadIdx.x;
  if (n >= N_) return;
  float xq[20];
#pragma unroll
  for (int k = 0; k < 20; k++) xq[k] = xh[n * 20 + k];
  float onw[15];   // layer-1 output at this new node (mean = 0: no incoming edge_0)
#pragma unroll
  for (int c = 0; c < HC_; c++) {
    float a = b1[c];
#pragma unroll
    for (int k = 0; k < 20; k++) a += xq[k] * w1r[c * 20 + k];
    onw[c] = fmaxf(a, 0.0f);
  }
  float mean[15];
#pragma unroll
  for (int c = 0; c < HC_; c++) mean[c] = 0.0f;
#pragma unroll
  for (int z = 0; z < K_; z++) {
    int idx = top5[n * 5 + z];
#pragma unroll
    for (int c = 0; c < HC_; c++) mean[c] += obase[idx * HC_ + c];
  }
#pragma unroll
  for (int c = 0; c < HC_; c++) mean[c] = mean[c] / 5.0f;
  float lg[3];
#pragma unroll
  for (int cl = 0; cl < 3; cl++) lg[cl] = blin[cl];
#pragma unroll
  for (int dd = 0; dd < 20; dd++) {
    float v = b2[dd];
#pragma unroll
    for (int c = 0; c < HC_; c++) v += mean[c] * w2l[dd * HC_ + c] + onw[c] * w2r[dd * HC_ + c];
#pragma unroll
    for (int cl = 0; cl < 3; cl++) lg[cl] += v * wlin[cl * 20 + dd];
  }
  float m = fmaxf(lg[0], fmaxf(lg[1], lg[2]));
  float e0 = expf(lg[0] - m), e1 = expf(lg[1] - m), e2 = expf(lg[2] - m);
  float s = e0 + e1 + e2;
  out[n * 3 + 0] = e0 / s;
  out[n * 3 + 1] = e1 / s;
  out[n * 3 + 2] = e2 / s;
}

extern "C" void kernel_launch(void* const* d_in, const int* in_sizes, int n_in,
                              void* d_out, int out_size, void* d_ws, size_t ws_size,
                              hipStream_t stream) {
  const float* x    = (const float*)d_in[0];
  const float* x0   = (const float*)d_in[1];
  const float* embw = (const float*)d_in[2];
  const float* Wih  = (const float*)d_in[3];
  const float* Whh  = (const float*)d_in[4];
  const float* bih  = (const float*)d_in[5];
  const float* bhh  = (const float*)d_in[6];
  const float* aw1  = (const float*)d_in[7];
  const float* ab1  = (const float*)d_in[8];
  const float* aw2  = (const float*)d_in[9];
  const float* ab2  = (const float*)d_in[10];
  const float* w1l  = (const float*)d_in[11];
  const float* w1r  = (const float*)d_in[12];
  const float* b1   = (const float*)d_in[13];
  const float* w2l  = (const float*)d_in[14];
  const float* w2r  = (const float*)d_in[15];
  const float* b2   = (const float*)d_in[16];
  const float* wlin = (const float*)d_in[17];
  const float* blin = (const float*)d_in[18];
  const int* edge0  = (const int*)d_in[19];

  float* ws    = (float*)d_ws;
  float* seq   = ws + OFF_SEQ;
  float* xh    = ws + OFF_XH;
  float* xhn   = ws + OFF_XHN;
  float* nx0   = ws + OFF_NX0;
  float* rx0   = ws + OFF_RX0;
  int*   top5  = (int*)(ws + OFF_TOP5);
  float* sum1  = ws + OFF_SUM1;
  float* cnt1  = ws + OFF_CNT1;
  float* obase = ws + OFF_OBASE;
  float* out   = (float*)d_out;

  hipMemsetAsync(sum1, 0, (size_t)(N0_ * H_ + N0_) * sizeof(float), stream);
  lstm_v16_kernel<true><<<N_ / 16, 256, 0, stream>>>(x, embw, Wih, Whh, bih, bhh, seq);
  for (int l = 1; l < 4; l++)
    lstm_v16_kernel<false><<<N_ / 16, 256, 0, stream>>>(x, embw, Wih + l * 1600,
                                                        Whh + l * 1600, bih + l * 80,
                                                        bhh + l * 80, seq);
  attn_kernel<<<N_ / 4, 256, 0, stream>>>(seq, aw1, ab1, aw2, ab2, xh, xhn);
  x0norm_kernel<<<(N0_ + 255) / 256, 256, 0, stream>>>(x0, nx0, rx0);
  topk_kernel<<<(N_ * 4) / 256, 256, 0, stream>>>(x0, xh, xhn, nx0, rx0, top5);
  scatter_kernel<<<(E0_ + 255) / 256, 256, 0, stream>>>(edge0, x0, sum1, cnt1);
  base_kernel<<<(N0_ + 255) / 256, 256, 0, stream>>>(x0, sum1, cnt1, w1l, w1r, b1, obase);
  final_kernel<<<N_ / 256, 256, 0, stream>>>(xh, top5, obase, w1r, b1, w2l, w2r, b2,
                                             wlin, blin, out);
}

// Round 7
// 2862.110 us; speedup vs baseline: 2.2590x; 2.2590x over previous
//
#include <hip/hip_runtime.h>
#include <math.h>

#define T_ 60
#define N_ 16384
#define C_ 5
#define H_ 20
#define G_ 80
#define HC_ 15
#define N0_ 3190
#define E0_ 31900
#define K_ 5

// workspace layout (float offsets)
#define OFF_SEQ   0
#define OFF_XH    (T_*N_*H_)            // 19,660,800
#define OFF_XHN   (OFF_XH + N_*H_)
#define OFF_NX0   (OFF_XHN + N_)
#define OFF_RX0   (OFF_NX0 + N0_)
#define OFF_TOP5  (OFF_RX0 + N0_)       // int[ N_*K_ ]
#define OFF_SUM1  (OFF_TOP5 + N_*K_)
#define OFF_CNT1  (OFF_SUM1 + N0_*H_)
#define OFF_OBASE (OFF_CNT1 + N0_)

__device__ __forceinline__ float sigf(float x) {
  return __fdividef(1.0f, 1.0f + __expf(-x));
}
__device__ __forceinline__ float tanhf_fast(float x) {
  float xc = fminf(fmaxf(x, -44.0f), 44.0f);
  float e = __expf(2.0f * xc);
  return __fdividef(e - 1.0f, e + 1.0f);
}

// ============================================================================
// LSTM layer "v16": 16 threads/element -> 4096 waves = 2 waves/SIMD with
// dense global I/O. Round-6 lesson: __launch_bounds__(256,3) forced VGPR=84
// -> scratch spill (FETCH 6.5GB, one 41ms dispatch). Now (256,2): 256-VGPR
// budget, 2 waves/SIMD still guaranteed (LDS 18.9KB x 2 blocks << 160KB).
//  - lane = slot*16 + rr; rr = q*4 + b owns rows 5rr..5rr+4 of the stacked
//    [80 x 40] [Wih|Whh]: all 5 rows are gate q, units 5b+j. 200 fmac/step.
//  - activation BEFORE gather (halves transcendentals); 20 ds_bpermute
//    exchange activated gates; h-feedback kept in PART order
//    hp[5d+j] = h_nat[5(b^d)+j] via 3x5 shfl_xor(1/2/3) (quad_perm DPP),
//    Whh columns pre-permuted at LDS-stage time (round-2-verified).
//  - natural h store: lane rr<4's own hn IS h_nat[5rr..] -> hst LDS, then
//    lanes rr<5 do dense 320B-span float4 global stores (fully-covered
//    wave span). Same for loads via double-buffered xst. All staging
//    intra-wave => ZERO barriers in the t-loop.
//  - weights LDS row stride 44 floats (16B aligned; worst 2-way alias=free).
// ============================================================================

#define WROW 44

template <bool FIRST>
__global__ void __launch_bounds__(256, 2) lstm_v16_kernel(
    const float* __restrict__ xg,      // [T, N, 5] raw codes (FIRST only)
    const float* __restrict__ embw,    // [5, 20]              (FIRST only)
    const float* __restrict__ Wih,     // [80, 20] this layer
    const float* __restrict__ Whh,     // [80, 20]
    const float* __restrict__ bih,     // [80]
    const float* __restrict__ bhh,     // [80]
    float* __restrict__ seq) {         // in (!FIRST) and out: [T, N, 20]
  __shared__ __align__(16) float wts[80 * WROW];
  __shared__ float bl2[80];
  __shared__ float embl[100];
  __shared__ __align__(16) float xst[2][16][20];
  __shared__ __align__(16) float hst[16][20];
  const int tid = threadIdx.x;

  // ---- stage weights: Wih cols natural, Whh cols part-permuted per row ----
  for (int idx = tid; idx < 80 * WROW; idx += 256) {
    int row = idx / WROW, col = idx % WROW;
    float v = 0.0f;
    if (col < 20) {
      v = Wih[row * 20 + col];
    } else if (col < 40) {
      int d = (col - 20) / 5, m = (col - 20) % 5;
      int br = (row / 5) & 3;
      v = Whh[row * 20 + ((br ^ d) * 5 + m)];
    }
    wts[idx] = v;
  }
  if (tid < 80) bl2[tid] = bih[tid] + bhh[tid];
  if (FIRST && tid < 100) embl[tid] = embw[tid];
  __syncthreads();

  const int lane = tid & 63;
  const int wv = tid >> 6;
  const int slot = lane >> 4;          // 0..3 element within wave
  const int rr = lane & 15;            // row-group
  const int q_g = rr >> 2;             // gate (0=i,1=f,2=g,3=o)
  const int b = rr & 3;                // unit block (units 5b..5b+4)
  const int e_blk = (wv << 2) + slot;  // element within block (0..15)
  const int n = (blockIdx.x << 4) + e_blk;
  const int wbase = rr * 5 * WROW;

  int srcA0, srcA1, srcA2, srcA3;      // bpermute byte addrs: lane slot*16+q*4+b
  srcA0 = ((slot << 4) + 0 + b) << 2;
  srcA1 = ((slot << 4) + 4 + b) << 2;
  srcA2 = ((slot << 4) + 8 + b) << 2;
  srcA3 = ((slot << 4) + 12 + b) << 2;

  float bs[5];
#pragma unroll
  for (int j = 0; j < 5; j++) bs[j] = bl2[rr * 5 + j];

  float hp[20], c[5];
#pragma unroll
  for (int k = 0; k < 20; k++) hp[k] = 0.0f;
#pragma unroll
  for (int j = 0; j < 5; j++) c[j] = 0.0f;

  // ---- initial input (t=0) into xst[0] (loader lanes rr<5, intra-wave) ----
  if (rr < 5) {
    if (FIRST) {
      xst[0][e_blk][rr] = xg[(size_t)n * 5 + rr];
    } else {
      float4 v = *reinterpret_cast<const float4*>(seq + (size_t)n * 20 + rr * 4);
      *reinterpret_cast<float4*>(&xst[0][e_blk][rr * 4]) = v;
    }
  }

  for (int t = 0; t < T_; t++) {
    const int cur = t & 1;
    // prefetch t+1 into regs (dense: 20 lanes/wave, 320B fully-covered span)
    float4 gx; float gf;
    if (rr < 5 && t + 1 < T_) {
      if (FIRST) {
        gf = xg[((size_t)(t + 1) * N_ + n) * 5 + rr];
      } else {
        gx = *reinterpret_cast<const float4*>(seq + ((size_t)(t + 1) * N_ + n) * 20 + rr * 4);
      }
    }
    // read current input from xst (broadcast within slot)
    float x[20];
    if (FIRST) {
      float raw0 = xst[cur][e_blk][0], raw1 = xst[cur][e_blk][1];
      float raw2 = xst[cur][e_blk][2], raw3 = xst[cur][e_blk][3];
      float raw4 = xst[cur][e_blk][4];
#pragma unroll
      for (int k = 0; k < 20; k++) {
        float a = raw0 * embl[k] + raw1 * embl[20 + k] + raw2 * embl[40 + k]
                + raw3 * embl[60 + k] + raw4 * embl[80 + k];
        x[k] = fmaxf(a, 0.f);
      }
    } else {
#pragma unroll
      for (int q = 0; q < 5; q++) {
        float4 v = *reinterpret_cast<const float4*>(&xst[cur][e_blk][q * 4]);
        x[4 * q] = v.x; x[4 * q + 1] = v.y; x[4 * q + 2] = v.z; x[4 * q + 3] = v.w;
      }
    }
    // 5 rows x 40 fmacs
    float av[5];
#pragma unroll
    for (int j = 0; j < 5; j++) {
      const float* wr = &wts[wbase + j * WROW];
      float a = bs[j];
#pragma unroll
      for (int k = 0; k < 20; k++) a += x[k] * wr[k];
#pragma unroll
      for (int k = 0; k < 20; k++) a += hp[k] * wr[20 + k];
      // own-gate activation (gate g uses tanh, others sigmoid)
      float sv = sigf(a);
      float tv = tanhf_fast(a);
      av[j] = (q_g == 2) ? tv : sv;
    }
    // gather activated gates for units 5b+j
    float hn[5];
#pragma unroll
    for (int j = 0; j < 5; j++) {
      int avi = __float_as_int(av[j]);
      float gi = __int_as_float(__builtin_amdgcn_ds_bpermute(srcA0, avi));
      float gf_ = __int_as_float(__builtin_amdgcn_ds_bpermute(srcA1, avi));
      float gg = __int_as_float(__builtin_amdgcn_ds_bpermute(srcA2, avi));
      float go = __int_as_float(__builtin_amdgcn_ds_bpermute(srcA3, avi));
      float cu = gf_ * c[j] + gi * gg;
      c[j] = cu;
      hn[j] = go * tanhf_fast(cu);
    }
    // part-order h feedback (quad_perm shuffles; compile-time positions)
#pragma unroll
    for (int j = 0; j < 5; j++) {
      hp[j] = hn[j];
      hp[5 + j] = __shfl_xor(hn[j], 1, 64);
      hp[10 + j] = __shfl_xor(hn[j], 2, 64);
      hp[15 + j] = __shfl_xor(hn[j], 3, 64);
    }
    // natural-order store via hst (intra-wave)
    if (rr < 4) {
#pragma unroll
      for (int j = 0; j < 5; j++) hst[e_blk][rr * 5 + j] = hn[j];
    }
    if (rr < 5) {
      float4 hv = *reinterpret_cast<const float4*>(&hst[e_blk][rr * 4]);
      *reinterpret_cast<float4*>(seq + ((size_t)t * N_ + n) * 20 + rr * 4) = hv;
      if (t + 1 < T_) {
        if (FIRST) xst[cur ^ 1][e_blk][rr] = gf;
        else *reinterpret_cast<float4*>(&xst[cur ^ 1][e_blk][rr * 4]) = gx;
      }
    }
  }
}

// ---------------- attention over T, one wave per element ----------------
__global__ void __launch_bounds__(256) attn_kernel(
    const float* __restrict__ seq, const float* __restrict__ w1,
    const float* __restrict__ b1v, const float* __restrict__ w2,
    const float* __restrict__ b2v, float* __restrict__ xh, float* __restrict__ xhn) {
  const int wv = threadIdx.x >> 6;
  const int t = threadIdx.x & 63;
  const int n = (blockIdx.x << 2) + wv;
  const bool act = (t < T_);
  float enc[20];
#pragma unroll
  for (int k = 0; k < 20; k++) enc[k] = 0.0f;
  if (act) {
    const float* p = seq + (t * N_ + n) * H_;
#pragma unroll
    for (int q = 0; q < 5; q++) {
      float4 v = *reinterpret_cast<const float4*>(p + 4 * q);
      enc[4 * q] = v.x; enc[4 * q + 1] = v.y; enc[4 * q + 2] = v.z; enc[4 * q + 3] = v.w;
    }
  }
  float e = -3.0e38f;
  if (act) {
    e = b2v[0];
#pragma unroll 4
    for (int k = 0; k < 64; k++) {
      float s = b1v[k];
      const float* wr = w1 + k * 20;
#pragma unroll
      for (int m = 0; m < 20; m++) s += wr[m] * enc[m];
      s = fmaxf(s, 0.0f);
      e += w2[k] * s;
    }
  }
  float mx = e;
#pragma unroll
  for (int d = 32; d; d >>= 1) mx = fmaxf(mx, __shfl_xor(mx, d, 64));
  float p_ = act ? __expf(e - mx) : 0.0f;
  float sm = p_;
#pragma unroll
  for (int d = 32; d; d >>= 1) sm += __shfl_xor(sm, d, 64);
  float w = __fdividef(p_, sm);
  float a[20];
#pragma unroll
  for (int k = 0; k < 20; k++) a[k] = enc[k] * w;
#pragma unroll
  for (int d = 1; d < 64; d <<= 1) {
#pragma unroll
    for (int k = 0; k < 20; k++) a[k] += __shfl_xor(a[k], d, 64);
  }
  if (t == 0) {
    float* op = xh + n * 20;
    float s2 = 0.0f;
#pragma unroll
    for (int k = 0; k < 20; k++) s2 += a[k] * a[k];
#pragma unroll
    for (int q = 0; q < 5; q++) {
      float4 v; v.x = a[4 * q]; v.y = a[4 * q + 1]; v.z = a[4 * q + 2]; v.w = a[4 * q + 3];
      *reinterpret_cast<float4*>(op + 4 * q) = v;
    }
    xhn[n] = sqrtf(s2);
  }
}

// ---------------- x0 norms ----------------
__global__ void __launch_bounds__(256) x0norm_kernel(const float* __restrict__ x0,
                                                     float* __restrict__ nx0,
                                                     float* __restrict__ rx0) {
  int j = blockIdx.x * 256 + threadIdx.x;
  if (j >= N0_) return;
  float s = 0.f;
#pragma unroll
  for (int k = 0; k < 20; k++) { float v = x0[j * 20 + k]; s += v * v; }
  float nv = sqrtf(s);
  nx0[j] = nv;
  rx0[j] = 1.0f / nv;
}

// ---------------- top-6 cosine, 4 lanes per row ----------------
__device__ __forceinline__ bool better_(float v1, int i1, float v2, int i2) {
  return (v1 > v2) || (v1 == v2 && i1 < i2);
}

__device__ __forceinline__ void merge6(float tv[6], int ti[6], int d) {
  float cv[12]; int ci[12];
#pragma unroll
  for (int z = 0; z < 6; z++) { cv[z] = tv[z]; ci[z] = ti[z]; }
#pragma unroll
  for (int z = 0; z < 6; z++) {
    cv[6 + z] = __shfl_xor(tv[z], d, 64);
    ci[6 + z] = __shfl_xor(ti[z], d, 64);
  }
#pragma unroll
  for (int o = 0; o < 6; o++) {
    float bv = -3.0e38f; int bi = 0x7fffffff; int bm = -1;
#pragma unroll
    for (int m = 0; m < 12; m++) {
      bool bt = better_(cv[m], ci[m], bv, bi);
      if (bt) { bv = cv[m]; bi = ci[m]; bm = m; }
    }
    tv[o] = bv; ti[o] = bi;
#pragma unroll
    for (int m = 0; m < 12; m++) if (m == bm) cv[m] = -3.0e38f;
  }
}

__global__ void __launch_bounds__(256) topk_kernel(
    const float* __restrict__ x0, const float* __restrict__ xh,
    const float* __restrict__ xhn, const float* __restrict__ nx0,
    const float* __restrict__ rx0, int* __restrict__ top5) {
  const int gt = blockIdx.x * 256 + threadIdx.x;
  const int i = gt >> 2, sub = gt & 3;
  float q[20];
  const float* qp = xh + i * 20;
#pragma unroll
  for (int z = 0; z < 5; z++) {
    float4 v = *reinterpret_cast<const float4*>(qp + 4 * z);
    q[4 * z] = v.x; q[4 * z + 1] = v.y; q[4 * z + 2] = v.z; q[4 * z + 3] = v.w;
  }
  float tv[6]; int ti[6];
#pragma unroll
  for (int z = 0; z < 6; z++) { tv[z] = -1.0e30f; ti[z] = 0x7fffffff; }
  for (int j = sub; j < N0_; j += 4) {
    const float* xr = x0 + j * 20;
    float d0 = 0.f;
#pragma unroll
    for (int k = 0; k < 20; k++) d0 += q[k] * xr[k];
    float key = d0 * rx0[j];
    if (key > tv[5]) {       // within-lane j ascending => strict > keeps stability
      tv[5] = key; ti[5] = j;
#pragma unroll
      for (int z = 5; z >= 1; z--) {
        bool sw = better_(tv[z], ti[z], tv[z - 1], ti[z - 1]);
        if (sw) {
          float fv = tv[z]; tv[z] = tv[z - 1]; tv[z - 1] = fv;
          int iv = ti[z]; ti[z] = ti[z - 1]; ti[z - 1] = iv;
        }
      }
    }
  }
  merge6(tv, ti, 1);
  merge6(tv, ti, 2);
  if (sub == 0) {
    const float* xr = x0 + ti[0] * 20;
    float d0 = 0.f;
#pragma unroll
    for (int k = 0; k < 20; k++) d0 += q[k] * xr[k];
    float a = (d0 / xhn[i]) / nx0[ti[0]];   // replicate ref's exact-match branch
    int base = (a == 1.0f) ? 1 : 0;
#pragma unroll
    for (int z = 0; z < 5; z++) top5[i * 5 + z] = ti[base + z];
  }
}

// ---------------- SAGE layer-1 aggregation over edge_0 ----------------
__global__ void __launch_bounds__(256) scatter_kernel(const int* __restrict__ edge,
                                                      const float* __restrict__ x0,
                                                      float* sum1, float* cnt1) {
  int e = blockIdx.x * 256 + threadIdx.x;
  if (e >= E0_) return;
  int s = edge[e], d = edge[E0_ + e];
  const float* xr = x0 + s * 20;
  float* dr = sum1 + d * 20;
#pragma unroll
  for (int k = 0; k < 20; k++) atomicAdd(dr + k, xr[k]);
  atomicAdd(cnt1 + d, 1.0f);
}

__global__ void __launch_bounds__(256) base_kernel(
    const float* __restrict__ x0, const float* __restrict__ sum1,
    const float* __restrict__ cnt1, const float* __restrict__ w1l,
    const float* __restrict__ w1r, const float* __restrict__ b1,
    float* __restrict__ obase) {
  int j = blockIdx.x * 256 + threadIdx.x;
  if (j >= N0_) return;
  float cm = fmaxf(cnt1[j], 1.0f);
  float mean[20], xv[20];
#pragma unroll
  for (int k = 0; k < 20; k++) {
    mean[k] = sum1[j * 20 + k] / cm;
    xv[k] = x0[j * 20 + k];
  }
#pragma unroll
  for (int c = 0; c < HC_; c++) {
    float a = b1[c];
#pragma unroll
    for (int k = 0; k < 20; k++) a += mean[k] * w1l[c * 20 + k];
#pragma unroll
    for (int k = 0; k < 20; k++) a += xv[k] * w1r[c * 20 + k];
    obase[j * HC_ + c] = fmaxf(a, 0.0f);
  }
}

// ---------------- SAGE layer-2 at new nodes + linear + softmax ----------------
__global__ void __launch_bounds__(256) final_kernel(
    const float* __restrict__ xh, const int* __restrict__ top5,
    const float* __restrict__ obase, const float* __restrict__ w1r,
    const float* __restrict__ b1, const float* __restrict__ w2l,
    const float* __restrict__ w2r, const float* __restrict__ b2,
    const float* __restrict__ wlin, const float* __restrict__ blin,
    float* __restrict__ out) {
  int n = blockIdx.x * 256 + threadIdx.x;
  if (n >= N_) return;
  float xq[20];
#pragma unroll
  for (int k = 0; k < 20; k++) xq[k] = xh[n * 20 + k];
  float onw[15];   // layer-1 output at this new node (mean = 0: no incoming edge_0)
#pragma unroll
  for (int c = 0; c < HC_; c++) {
    float a = b1[c];
#pragma unroll
    for (int k = 0; k < 20; k++) a += xq[k] * w1r[c * 20 + k];
    onw[c] = fmaxf(a, 0.0f);
  }
  float mean[15];
#pragma unroll
  for (int c = 0; c < HC_; c++) mean[c] = 0.0f;
#pragma unroll
  for (int z = 0; z < K_; z++) {
    int idx = top5[n * 5 + z];
#pragma unroll
    for (int c = 0; c < HC_; c++) mean[c] += obase[idx * HC_ + c];
  }
#pragma unroll
  for (int c = 0; c < HC_; c++) mean[c] = mean[c] / 5.0f;
  float lg[3];
#pragma unroll
  for (int cl = 0; cl < 3; cl++) lg[cl] = blin[cl];
#pragma unroll
  for (int dd = 0; dd < 20; dd++) {
    float v = b2[dd];
#pragma unroll
    for (int c = 0; c < HC_; c++) v += mean[c] * w2l[dd * HC_ + c] + onw[c] * w2r[dd * HC_ + c];
#pragma unroll
    for (int cl = 0; cl < 3; cl++) lg[cl] += v * wlin[cl * 20 + dd];
  }
  float m = fmaxf(lg[0], fmaxf(lg[1], lg[2]));
  float e0 = expf(lg[0] - m), e1 = expf(lg[1] - m), e2 = expf(lg[2] - m);
  float s = e0 + e1 + e2;
  out[n * 3 + 0] = e0 / s;
  out[n * 3 + 1] = e1 / s;
  out[n * 3 + 2] = e2 / s;
}

extern "C" void kernel_launch(void* const* d_in, const int* in_sizes, int n_in,
                              void* d_out, int out_size, void* d_ws, size_t ws_size,
                              hipStream_t stream) {
  const float* x    = (const float*)d_in[0];
  const float* x0   = (const float*)d_in[1];
  const float* embw = (const float*)d_in[2];
  const float* Wih  = (const float*)d_in[3];
  const float* Whh  = (const float*)d_in[4];
  const float* bih  = (const float*)d_in[5];
  const float* bhh  = (const float*)d_in[6];
  const float* aw1  = (const float*)d_in[7];
  const float* ab1  = (const float*)d_in[8];
  const float* aw2  = (const float*)d_in[9];
  const float* ab2  = (const float*)d_in[10];
  const float* w1l  = (const float*)d_in[11];
  const float* w1r  = (const float*)d_in[12];
  const float* b1   = (const float*)d_in[13];
  const float* w2l  = (const float*)d_in[14];
  const float* w2r  = (const float*)d_in[15];
  const float* b2   = (const float*)d_in[16];
  const float* wlin = (const float*)d_in[17];
  const float* blin = (const float*)d_in[18];
  const int* edge0  = (const int*)d_in[19];

  float* ws    = (float*)d_ws;
  float* seq   = ws + OFF_SEQ;
  float* xh    = ws + OFF_XH;
  float* xhn   = ws + OFF_XHN;
  float* nx0   = ws + OFF_NX0;
  float* rx0   = ws + OFF_RX0;
  int*   top5  = (int*)(ws + OFF_TOP5);
  float* sum1  = ws + OFF_SUM1;
  float* cnt1  = ws + OFF_CNT1;
  float* obase = ws + OFF_OBASE;
  float* out   = (float*)d_out;

  hipMemsetAsync(sum1, 0, (size_t)(N0_ * H_ + N0_) * sizeof(float), stream);
  lstm_v16_kernel<true><<<N_ / 16, 256, 0, stream>>>(x, embw, Wih, Whh, bih, bhh, seq);
  for (int l = 1; l < 4; l++)
    lstm_v16_kernel<false><<<N_ / 16, 256, 0, stream>>>(x, embw, Wih + l * 1600,
                                                        Whh + l * 1600, bih + l * 80,
                                                        bhh + l * 80, seq);
  attn_kernel<<<N_ / 4, 256, 0, stream>>>(seq, aw1, ab1, aw2, ab2, xh, xhn);
  x0norm_kernel<<<(N0_ + 255) / 256, 256, 0, stream>>>(x0, nx0, rx0);
  topk_kernel<<<(N_ * 4) / 256, 256, 0, stream>>>(x0, xh, xhn, nx0, rx0, top5);
  scatter_kernel<<<(E0_ + 255) / 256, 256, 0, stream>>>(edge0, x0, sum1, cnt1);
  base_kernel<<<(N0_ + 255) / 256, 256, 0, stream>>>(x0, sum1, cnt1, w1l, w1r, b1, obase);
  final_kernel<<<N_ / 256, 256, 0, stream>>>(xh, top5, obase, w1r, b1, w2l, w2r, b2,
                                             wlin, blin, out);
}

// Round 8
// 2360.225 us; speedup vs baseline: 2.7394x; 1.2126x over previous
//
#include <hip/hip_runtime.h>
#include <math.h>

#define T_ 60
#define N_ 16384
#define C_ 5
#define H_ 20
#define G_ 80
#define HC_ 15
#define N0_ 3190
#define E0_ 31900
#define K_ 5

// workspace layout (float offsets)
#define OFF_SEQ   0
#define OFF_XH    (T_*N_*H_)            // 19,660,800
#define OFF_XHN   (OFF_XH + N_*H_)
#define OFF_NX0   (OFF_XHN + N_)
#define OFF_RX0   (OFF_NX0 + N0_)
#define OFF_TOP5  (OFF_RX0 + N0_)       // int[ N_*K_ ]
#define OFF_SUM1  (OFF_TOP5 + N_*K_)
#define OFF_CNT1  (OFF_SUM1 + N0_*H_)
#define OFF_OBASE (OFF_CNT1 + N0_)

__device__ __forceinline__ float sigf(float x) {
  return __fdividef(1.0f, 1.0f + __expf(-x));
}
__device__ __forceinline__ float tanhf_fast(float x) {
  float xc = fminf(fmaxf(x, -44.0f), 44.0f);
  float e = __expf(2.0f * xc);
  return __fdividef(e - 1.0f, e + 1.0f);
}

// ============================================================================
// LSTM layer "gemm8": WEIGHTS-STATIONARY-IN-REGISTERS. Rounds 1-7 all
// streamed weights from LDS every step (~200 b128/wave-step -> LDS-pipe
// bound ~400+ us/layer). Here the per-step compute is the tiny GEMM
// G[80,8] = W[80,40] x Z[40,8] (Z=[x;h]) with W cached in VGPRs.
//  - block: 512 thr = 8 waves, 8 elements. wave w owns rows w*10..w*10+9;
//    lane = el(3b)|cg(3b); thread holds W[10 rows][5 cols] = 50 VGPRs,
//    loaded once via LDS stage. 50 fmacs/step/thread.
//  - col-combine: in-wave butterfly shfl_xor(1,2,4) over cg bits.
//  - raw gates -> LDS Graw[8][84]; barrier; update phase (tid<160 = (el,u)):
//    +bias, activations, c/h in regs, h -> Z and DENSE dword store to seq
//    (block slice = 640 B contiguous, full cache lines).
//  - x-prefetch: 40 loader lanes (tid 160..199) issue dense loads at phase-A
//    start, write to Z/xraw after compute (latency hidden under fmacs).
//  - NO weight/h permutations anywhere - all natural order.
//  - 2 barriers/step; LDS ~17 KB; est ~100 VGPR -> 4 waves/SIMD.
// ============================================================================

template <bool FIRST>
__global__ void __launch_bounds__(512, 2) lstm_gemm_kernel(
    const float* __restrict__ xg,      // [T, N, 5] raw codes (FIRST only)
    const float* __restrict__ embw,    // [5, 20]              (FIRST only)
    const float* __restrict__ Wih,     // [80, 20] this layer
    const float* __restrict__ Whh,     // [80, 20]
    const float* __restrict__ bih,     // [80]
    const float* __restrict__ bhh,     // [80]
    float* __restrict__ seq) {         // in (!FIRST) and out: [T, N, 20]
  __shared__ __align__(16) float wst[3200];     // staged [80][40] = [Wih|Whh]
  __shared__ __align__(16) float Z[8][44];      // per element: x[20] | h[20]
  __shared__ __align__(16) float Graw[8][84];   // raw pre-activations [el][row]
  __shared__ float xraw[40];                    // FIRST: 8 els x 5 codes
  const int tid = threadIdx.x;
  const int w = tid >> 6;            // wave: rows w*10 .. w*10+9
  const int lane = tid & 63;
  const int el = lane >> 3;          // element 0..7
  const int cg = lane & 7;           // col group: cols cg*5 .. cg*5+4
  const int bidx = blockIdx.x;

  // ---- stage stacked weights to LDS (once) ----
  for (int i = tid; i < 3200; i += 512) {
    int r = i / 40, col = i % 40;
    wst[i] = (col < 20) ? Wih[r * 20 + col] : Whh[r * 20 + (col - 20)];
  }
  __syncthreads();

  // ---- weight registers: W[10][5] ----
  float wreg[10][5];
  {
    const float* base = &wst[(w * 10) * 40 + cg * 5];
#pragma unroll
    for (int j = 0; j < 10; j++)
#pragma unroll
      for (int m = 0; m < 5; m++) wreg[j][m] = base[j * 40 + m];
  }

  // ---- update-thread constants (tid < 160: el=tid/20, u=tid%20) ----
  const bool isUpd = (tid < 160);
  const int uel = tid / 20;
  const int uu = tid % 20;
  float bi = 0, bf = 0, bg = 0, bo = 0;
  float ew0 = 0, ew1 = 0, ew2 = 0, ew3 = 0, ew4 = 0;
  if (isUpd) {
    bi = bih[uu] + bhh[uu];
    bf = bih[20 + uu] + bhh[20 + uu];
    bg = bih[40 + uu] + bhh[40 + uu];
    bo = bih[60 + uu] + bhh[60 + uu];
    if (FIRST) {
      ew0 = embw[uu]; ew1 = embw[20 + uu]; ew2 = embw[40 + uu];
      ew3 = embw[60 + uu]; ew4 = embw[80 + uu];
    }
  }
  const bool isLd = (tid >= 160 && tid < 200);
  const int lk = tid - 160;          // 0..39

  // ---- prologue: fill Z for t=0 ----
  if (FIRST) {
    if (isLd) xraw[lk] = xg[(size_t)bidx * 40 + lk];
  } else {
    if (isLd) {
      float4 v = *reinterpret_cast<const float4*>(seq + (size_t)bidx * 160 + lk * 4);
      *reinterpret_cast<float4*>(&Z[lk / 5][(lk % 5) * 4]) = v;
    }
  }
  if (isUpd) Z[uel][20 + uu] = 0.0f;
  __syncthreads();
  if (FIRST) {
    if (isUpd) {
      float a = xraw[uel * 5 + 0] * ew0 + xraw[uel * 5 + 1] * ew1
              + xraw[uel * 5 + 2] * ew2 + xraw[uel * 5 + 3] * ew3
              + xraw[uel * 5 + 4] * ew4;
      Z[uel][uu] = fmaxf(a, 0.0f);
    }
    __syncthreads();
  }

  float cst = 0.0f;                  // cell state (update threads)
  const size_t outbase = (size_t)bidx * 160 + tid;

  for (int t = 0; t < T_; t++) {
    // ---------------- phase A: GEMM ----------------
    float4 gx;
    float gcode;
    if (t + 1 < T_) {   // issue prefetch early; consume after compute
      if (FIRST) {
        if (isLd) gcode = xg[(size_t)(t + 1) * (N_ * 5) + bidx * 40 + lk];
      } else {
        if (isLd)
          gx = *reinterpret_cast<const float4*>(
              seq + (size_t)(t + 1) * (N_ * 20) + bidx * 160 + lk * 4);
      }
    }
    const float* zp = &Z[el][cg * 5];
    float z0 = zp[0], z1 = zp[1], z2 = zp[2], z3 = zp[3], z4 = zp[4];
    float acc[10];
#pragma unroll
    for (int j = 0; j < 10; j++) {
      acc[j] = wreg[j][0] * z0 + wreg[j][1] * z1 + wreg[j][2] * z2
             + wreg[j][3] * z3 + wreg[j][4] * z4;
    }
    // butterfly sum over the 8 col-groups (lane bits 0-2)
#pragma unroll
    for (int j = 0; j < 10; j++) acc[j] += __shfl_xor(acc[j], 1, 64);
#pragma unroll
    for (int j = 0; j < 10; j++) acc[j] += __shfl_xor(acc[j], 2, 64);
#pragma unroll
    for (int j = 0; j < 10; j++) acc[j] += __shfl_xor(acc[j], 4, 64);
    // write raw rows (predicated, static reg indices, b64-aligned)
    {
      float* gp = &Graw[el][w * 10];
      float2 v;
      if (cg == 0) { v.x = acc[0]; v.y = acc[1]; *reinterpret_cast<float2*>(gp + 0) = v; }
      if (cg == 1) { v.x = acc[2]; v.y = acc[3]; *reinterpret_cast<float2*>(gp + 2) = v; }
      if (cg == 2) { v.x = acc[4]; v.y = acc[5]; *reinterpret_cast<float2*>(gp + 4) = v; }
      if (cg == 3) { v.x = acc[6]; v.y = acc[7]; *reinterpret_cast<float2*>(gp + 6) = v; }
      if (cg == 4) { v.x = acc[8]; v.y = acc[9]; *reinterpret_cast<float2*>(gp + 8) = v; }
    }
    if (FIRST && isLd && t + 1 < T_) xraw[lk] = gcode;  // read only in phase B
    __syncthreads();
    // ---------------- phase B: gates / state / IO ----------------
    if (isUpd) {
      float gi = Graw[uel][uu] + bi;
      float gf = Graw[uel][20 + uu] + bf;
      float gg = Graw[uel][40 + uu] + bg;
      float go = Graw[uel][60 + uu] + bo;
      float si = sigf(gi), sf = sigf(gf);
      float tg = tanhf_fast(gg), so = sigf(go);
      cst = sf * cst + si * tg;
      float h = so * tanhf_fast(cst);
      seq[(size_t)t * (N_ * 20) + outbase] = h;   // dense: block slice 640 B
      Z[uel][20 + uu] = h;
      if (FIRST && t + 1 < T_) {   // embed x_{t+1} (codes staged in phase A)
        float a = xraw[uel * 5 + 0] * ew0 + xraw[uel * 5 + 1] * ew1
                + xraw[uel * 5 + 2] * ew2 + xraw[uel * 5 + 3] * ew3
                + xraw[uel * 5 + 4] * ew4;
        Z[uel][uu] = fmaxf(a, 0.0f);
      }
    }
    if (!FIRST && isLd && t + 1 < T_) {
      *reinterpret_cast<float4*>(&Z[lk / 5][(lk % 5) * 4]) = gx;
    }
    __syncthreads();
  }
}

// ---------------- attention over T, one wave per element ----------------
__global__ void __launch_bounds__(256) attn_kernel(
    const float* __restrict__ seq, const float* __restrict__ w1,
    const float* __restrict__ b1v, const float* __restrict__ w2,
    const float* __restrict__ b2v, float* __restrict__ xh, float* __restrict__ xhn) {
  const int wv = threadIdx.x >> 6;
  const int t = threadIdx.x & 63;
  const int n = (blockIdx.x << 2) + wv;
  const bool act = (t < T_);
  float enc[20];
#pragma unroll
  for (int k = 0; k < 20; k++) enc[k] = 0.0f;
  if (act) {
    const float* p = seq + (t * N_ + n) * H_;
#pragma unroll
    for (int q = 0; q < 5; q++) {
      float4 v = *reinterpret_cast<const float4*>(p + 4 * q);
      enc[4 * q] = v.x; enc[4 * q + 1] = v.y; enc[4 * q + 2] = v.z; enc[4 * q + 3] = v.w;
    }
  }
  float e = -3.0e38f;
  if (act) {
    e = b2v[0];
#pragma unroll 4
    for (int k = 0; k < 64; k++) {
      float s = b1v[k];
      const float* wr = w1 + k * 20;
#pragma unroll
      for (int m = 0; m < 20; m++) s += wr[m] * enc[m];
      s = fmaxf(s, 0.0f);
      e += w2[k] * s;
    }
  }
  float mx = e;
#pragma unroll
  for (int d = 32; d; d >>= 1) mx = fmaxf(mx, __shfl_xor(mx, d, 64));
  float p_ = act ? __expf(e - mx) : 0.0f;
  float sm = p_;
#pragma unroll
  for (int d = 32; d; d >>= 1) sm += __shfl_xor(sm, d, 64);
  float w = __fdividef(p_, sm);
  float a[20];
#pragma unroll
  for (int k = 0; k < 20; k++) a[k] = enc[k] * w;
#pragma unroll
  for (int d = 1; d < 64; d <<= 1) {
#pragma unroll
    for (int k = 0; k < 20; k++) a[k] += __shfl_xor(a[k], d, 64);
  }
  if (t == 0) {
    float* op = xh + n * 20;
    float s2 = 0.0f;
#pragma unroll
    for (int k = 0; k < 20; k++) s2 += a[k] * a[k];
#pragma unroll
    for (int q = 0; q < 5; q++) {
      float4 v; v.x = a[4 * q]; v.y = a[4 * q + 1]; v.z = a[4 * q + 2]; v.w = a[4 * q + 3];
      *reinterpret_cast<float4*>(op + 4 * q) = v;
    }
    xhn[n] = sqrtf(s2);
  }
}

// ---------------- x0 norms ----------------
__global__ void __launch_bounds__(256) x0norm_kernel(const float* __restrict__ x0,
                                                     float* __restrict__ nx0,
                                                     float* __restrict__ rx0) {
  int j = blockIdx.x * 256 + threadIdx.x;
  if (j >= N0_) return;
  float s = 0.f;
#pragma unroll
  for (int k = 0; k < 20; k++) { float v = x0[j * 20 + k]; s += v * v; }
  float nv = sqrtf(s);
  nx0[j] = nv;
  rx0[j] = 1.0f / nv;
}

// ---------------- top-6 cosine, 4 lanes per row ----------------
__device__ __forceinline__ bool better_(float v1, int i1, float v2, int i2) {
  return (v1 > v2) || (v1 == v2 && i1 < i2);
}

__device__ __forceinline__ void merge6(float tv[6], int ti[6], int d) {
  float cv[12]; int ci[12];
#pragma unroll
  for (int z = 0; z < 6; z++) { cv[z] = tv[z]; ci[z] = ti[z]; }
#pragma unroll
  for (int z = 0; z < 6; z++) {
    cv[6 + z] = __shfl_xor(tv[z], d, 64);
    ci[6 + z] = __shfl_xor(ti[z], d, 64);
  }
#pragma unroll
  for (int o = 0; o < 6; o++) {
    float bv = -3.0e38f; int bi = 0x7fffffff; int bm = -1;
#pragma unroll
    for (int m = 0; m < 12; m++) {
      bool bt = better_(cv[m], ci[m], bv, bi);
      if (bt) { bv = cv[m]; bi = ci[m]; bm = m; }
    }
    tv[o] = bv; ti[o] = bi;
#pragma unroll
    for (int m = 0; m < 12; m++) if (m == bm) cv[m] = -3.0e38f;
  }
}

__global__ void __launch_bounds__(256) topk_kernel(
    const float* __restrict__ x0, const float* __restrict__ xh,
    const float* __restrict__ xhn, const float* __restrict__ nx0,
    const float* __restrict__ rx0, int* __restrict__ top5) {
  const int gt = blockIdx.x * 256 + threadIdx.x;
  const int i = gt >> 2, sub = gt & 3;
  float q[20];
  const float* qp = xh + i * 20;
#pragma unroll
  for (int z = 0; z < 5; z++) {
    float4 v = *reinterpret_cast<const float4*>(qp + 4 * z);
    q[4 * z] = v.x; q[4 * z + 1] = v.y; q[4 * z + 2] = v.z; q[4 * z + 3] = v.w;
  }
  float tv[6]; int ti[6];
#pragma unroll
  for (int z = 0; z < 6; z++) { tv[z] = -1.0e30f; ti[z] = 0x7fffffff; }
  for (int j = sub; j < N0_; j += 4) {
    const float* xr = x0 + j * 20;
    float d0 = 0.f;
#pragma unroll
    for (int k = 0; k < 20; k++) d0 += q[k] * xr[k];
    float key = d0 * rx0[j];
    if (key > tv[5]) {       // within-lane j ascending => strict > keeps stability
      tv[5] = key; ti[5] = j;
#pragma unroll
      for (int z = 5; z >= 1; z--) {
        bool sw = better_(tv[z], ti[z], tv[z - 1], ti[z - 1]);
        if (sw) {
          float fv = tv[z]; tv[z] = tv[z - 1]; tv[z - 1] = fv;
          int iv = ti[z]; ti[z] = ti[z - 1]; ti[z - 1] = iv;
        }
      }
    }
  }
  merge6(tv, ti, 1);
  merge6(tv, ti, 2);
  if (sub == 0) {
    const float* xr = x0 + ti[0] * 20;
    float d0 = 0.f;
#pragma unroll
    for (int k = 0; k < 20; k++) d0 += q[k] * xr[k];
    float a = (d0 / xhn[i]) / nx0[ti[0]];   // replicate ref's exact-match branch
    int base = (a == 1.0f) ? 1 : 0;
#pragma unroll
    for (int z = 0; z < 5; z++) top5[i * 5 + z] = ti[base + z];
  }
}

// ---------------- SAGE layer-1 aggregation over edge_0 ----------------
__global__ void __launch_bounds__(256) scatter_kernel(const int* __restrict__ edge,
                                                      const float* __restrict__ x0,
                                                      float* sum1, float* cnt1) {
  int e = blockIdx.x * 256 + threadIdx.x;
  if (e >= E0_) return;
  int s = edge[e], d = edge[E0_ + e];
  const float* xr = x0 + s * 20;
  float* dr = sum1 + d * 20;
#pragma unroll
  for (int k = 0; k < 20; k++) atomicAdd(dr + k, xr[k]);
  atomicAdd(cnt1 + d, 1.0f);
}

__global__ void __launch_bounds__(256) base_kernel(
    const float* __restrict__ x0, const float* __restrict__ sum1,
    const float* __restrict__ cnt1, const float* __restrict__ w1l,
    const float* __restrict__ w1r, const float* __restrict__ b1,
    float* __restrict__ obase) {
  int j = blockIdx.x * 256 + threadIdx.x;
  if (j >= N0_) return;
  float cm = fmaxf(cnt1[j], 1.0f);
  float mean[20], xv[20];
#pragma unroll
  for (int k = 0; k < 20; k++) {
    mean[k] = sum1[j * 20 + k] / cm;
    xv[k] = x0[j * 20 + k];
  }
#pragma unroll
  for (int c = 0; c < HC_; c++) {
    float a = b1[c];
#pragma unroll
    for (int k = 0; k < 20; k++) a += mean[k] * w1l[c * 20 + k];
#pragma unroll
    for (int k = 0; k < 20; k++) a += xv[k] * w1r[c * 20 + k];
    obase[j * HC_ + c] = fmaxf(a, 0.0f);
  }
}

// ---------------- SAGE layer-2 at new nodes + linear + softmax ----------------
__global__ void __launch_bounds__(256) final_kernel(
    const float* __restrict__ xh, const int* __restrict__ top5,
    const float* __restrict__ obase, const float* __restrict__ w1r,
    const float* __restrict__ b1, const float* __restrict__ w2l,
    const float* __restrict__ w2r, const float* __restrict__ b2,
    const float* __restrict__ wlin, const float* __restrict__ blin,
    float* __restrict__ out) {
  int n = blockIdx.x * 256 + threadIdx.x;
  if (n >= N_) return;
  float xq[20];
#pragma unroll
  for (int k = 0; k < 20; k++) xq[k] = xh[n * 20 + k];
  float onw[15];   // layer-1 output at this new node (mean = 0: no incoming edge_0)
#pragma unroll
  for (int c = 0; c < HC_; c++) {
    float a = b1[c];
#pragma unroll
    for (int k = 0; k < 20; k++) a += xq[k] * w1r[c * 20 + k];
    onw[c] = fmaxf(a, 0.0f);
  }
  float mean[15];
#pragma unroll
  for (int c = 0; c < HC_; c++) mean[c] = 0.0f;
#pragma unroll
  for (int z = 0; z < K_; z++) {
    int idx = top5[n * 5 + z];
#pragma unroll
    for (int c = 0; c < HC_; c++) mean[c] += obase[idx * HC_ + c];
  }
#pragma unroll
  for (int c = 0; c < HC_; c++) mean[c] = mean[c] / 5.0f;
  float lg[3];
#pragma unroll
  for (int cl = 0; cl < 3; cl++) lg[cl] = blin[cl];
#pragma unroll
  for (int dd = 0; dd < 20; dd++) {
    float v = b2[dd];
#pragma unroll
    for (int c = 0; c < HC_; c++) v += mean[c] * w2l[dd * HC_ + c] + onw[c] * w2r[dd * HC_ + c];
#pragma unroll
    for (int cl = 0; cl < 3; cl++) lg[cl] += v * wlin[cl * 20 + dd];
  }
  float m = fmaxf(lg[0], fmaxf(lg[1], lg[2]));
  float e0 = expf(lg[0] - m), e1 = expf(lg[1] - m), e2 = expf(lg[2] - m);
  float s = e0 + e1 + e2;
  out[n * 3 + 0] = e0 / s;
  out[n * 3 + 1] = e1 / s;
  out[n * 3 + 2] = e2 / s;
}

extern "C" void kernel_launch(void* const* d_in, const int* in_sizes, int n_in,
                              void* d_out, int out_size, void* d_ws, size_t ws_size,
                              hipStream_t stream) {
  const float* x    = (const float*)d_in[0];
  const float* x0   = (const float*)d_in[1];
  const float* embw = (const float*)d_in[2];
  const float* Wih  = (const float*)d_in[3];
  const float* Whh  = (const float*)d_in[4];
  const float* bih  = (const float*)d_in[5];
  const float* bhh  = (const float*)d_in[6];
  const float* aw1  = (const float*)d_in[7];
  const float* ab1  = (const float*)d_in[8];
  const float* aw2  = (const float*)d_in[9];
  const float* ab2  = (const float*)d_in[10];
  const float* w1l  = (const float*)d_in[11];
  const float* w1r  = (const float*)d_in[12];
  const float* b1   = (const float*)d_in[13];
  const float* w2l  = (const float*)d_in[14];
  const float* w2r  = (const float*)d_in[15];
  const float* b2   = (const float*)d_in[16];
  const float* wlin = (const float*)d_in[17];
  const float* blin = (const float*)d_in[18];
  const int* edge0  = (const int*)d_in[19];

  float* ws    = (float*)d_ws;
  float* seq   = ws + OFF_SEQ;
  float* xh    = ws + OFF_XH;
  float* xhn   = ws + OFF_XHN;
  float* nx0   = ws + OFF_NX0;
  float* rx0   = ws + OFF_RX0;
  int*   top5  = (int*)(ws + OFF_TOP5);
  float* sum1  = ws + OFF_SUM1;
  float* cnt1  = ws + OFF_CNT1;
  float* obase = ws + OFF_OBASE;
  float* out   = (float*)d_out;

  hipMemsetAsync(sum1, 0, (size_t)(N0_ * H_ + N0_) * sizeof(float), stream);
  lstm_gemm_kernel<true><<<N_ / 8, 512, 0, stream>>>(x, embw, Wih, Whh, bih, bhh, seq);
  for (int l = 1; l < 4; l++)
    lstm_gemm_kernel<false><<<N_ / 8, 512, 0, stream>>>(x, embw, Wih + l * 1600,
                                                        Whh + l * 1600, bih + l * 80,
                                                        bhh + l * 80, seq);
  attn_kernel<<<N_ / 4, 256, 0, stream>>>(seq, aw1, ab1, aw2, ab2, xh, xhn);
  x0norm_kernel<<<(N0_ + 255) / 256, 256, 0, stream>>>(x0, nx0, rx0);
  topk_kernel<<<(N_ * 4) / 256, 256, 0, stream>>>(x0, xh, xhn, nx0, rx0, top5);
  scatter_kernel<<<(E0_ + 255) / 256, 256, 0, stream>>>(edge0, x0, sum1, cnt1);
  base_kernel<<<(N0_ + 255) / 256, 256, 0, stream>>>(x0, sum1, cnt1, w1l, w1r, b1, obase);
  final_kernel<<<N_ / 256, 256, 0, stream>>>(xh, top5, obase, w1r, b1, w2l, w2r, b2,
                                             wlin, blin, out);
}

// Round 9
// 1469.865 us; speedup vs baseline: 4.3987x; 1.6057x over previous
//
#include <hip/hip_runtime.h>
#include <math.h>

#define T_ 60
#define N_ 16384
#define C_ 5
#define H_ 20
#define G_ 80
#define HC_ 15
#define N0_ 3190
#define E0_ 31900
#define K_ 5

// workspace layout (float offsets)
#define OFF_SEQ   0
#define OFF_XH    (T_*N_*H_)            // 19,660,800
#define OFF_XHN   (OFF_XH + N_*H_)
#define OFF_NX0   (OFF_XHN + N_)
#define OFF_RX0   (OFF_NX0 + N0_)
#define OFF_TOP5  (OFF_RX0 + N0_)       // int[ N_*K_ ]
#define OFF_SUM1  (OFF_TOP5 + N_*K_)
#define OFF_CNT1  (OFF_SUM1 + N0_*H_)
#define OFF_OBASE (OFF_CNT1 + N0_)

__device__ __forceinline__ float sigf(float x) {
  return __fdividef(1.0f, 1.0f + __expf(-x));
}
__device__ __forceinline__ float tanhf_fast(float x) {
  float xc = fminf(fmaxf(x, -44.0f), 44.0f);
  float e = __expf(2.0f * xc);
  return __fdividef(e - 1.0f, e + 1.0f);
}

// ============================================================================
// LSTM layer "wpe": WAVE-PER-ELEMENT, weights pinned in VGPRs.
// Round-8 lesson: compiler rematerialized the 50 weight regs back into
// in-loop LDS reads (VGPR=48, 1.1e7 bank conflicts). Fix: asm-pin.
//  - lane = rg(4b)*4 + cg(2b). Thread owns rows rg*5..+4 x cols cg*10..+9
//    of stacked [80x40] [Wih|Whh] = 50 weights in VGPRs (opaque via asm).
//  - per step: 3 LDS z-reads (b128/b64, 4-addr broadcast, conflict-free),
//    50 fmacs, col-combine shfl_xor(1)+shfl_xor(2) = quad_perm DPP (VALU
//    pipe, NOT DS), cg==0 writes 80 raw gates to per-wave gr[], intra-wave
//    waitcnt (NO barrier), lanes u<20 do gates/c/h, dense 80B seq store,
//    h back to per-wave zb[]. Zero barriers in t-loop; waves fully
//    independent; per-wave LDS regions.
//  - DS ops/step ~14 (vs ~200 round 1); global I/O 20-lane contiguous
//    spans (round-8-verified exact FETCH/WRITE).
// ============================================================================

#define LWV 160   // per-wave LDS region (floats): zb[48] | gr@64[80] | raw@144

template <bool FIRST>
__global__ void __launch_bounds__(256, 2) lstm_wpe_kernel(
    const float* __restrict__ xg,      // [T, N, 5] raw codes (FIRST only)
    const float* __restrict__ embw,    // [5, 20]              (FIRST only)
    const float* __restrict__ Wih,     // [80, 20] this layer
    const float* __restrict__ Whh,     // [80, 20]
    const float* __restrict__ bih,     // [80]
    const float* __restrict__ bhh,     // [80]
    float* __restrict__ seq) {         // in (!FIRST) and out: [T, N, 20]
  __shared__ __align__(16) float wst[3200];     // staged [80][40]
  __shared__ __align__(16) float wsh[4 * LWV];  // per-wave regions
  const int tid = threadIdx.x;

  for (int i = tid; i < 3200; i += 256) {
    int r = i / 40, col = i % 40;
    wst[i] = (col < 20) ? Wih[r * 20 + col] : Whh[r * 20 + (col - 20)];
  }
  __syncthreads();

  const int lane = tid & 63;
  const int w = tid >> 6;
  const int rg = lane >> 2;            // row group: rows rg*5..rg*5+4
  const int cg = lane & 3;             // col group: cols cg*10..cg*10+9
  const int n = (blockIdx.x << 2) + w; // this wave's element
  float* zb  = &wsh[w * LWV];          // z slots: [4 slots][12] (slot s = cols s*10..+9)
  float* gr  = &wsh[w * LWV + 64];     // raw gates [80]
  float* raw = &wsh[w * LWV + 144];    // FIRST: 5 codes

  // ---- weight registers (pinned: opaque to the compiler => no remat) ----
  float wr[5][10];
  {
    const float* bp = &wst[(rg * 5) * 40 + cg * 10];
#pragma unroll
    for (int j = 0; j < 5; j++)
#pragma unroll
      for (int m = 0; m < 10; m++) wr[j][m] = bp[j * 40 + m];
  }
#pragma unroll
  for (int j = 0; j < 5; j++)
#pragma unroll
    for (int m = 0; m < 10; m++) asm volatile("" : "+v"(wr[j][m]));

  const bool isU = (lane < 20);
  const int u = isU ? lane : 0;
  const float bi = bih[u] + bhh[u];
  const float bf = bih[20 + u] + bhh[20 + u];
  const float bg = bih[40 + u] + bhh[40 + u];
  const float bo = bih[60 + u] + bhh[60 + u];
  float e0 = 0, e1 = 0, e2 = 0, e3 = 0, e4 = 0;
  if (FIRST) {
    e0 = embw[u]; e1 = embw[20 + u]; e2 = embw[40 + u];
    e3 = embw[60 + u]; e4 = embw[80 + u];
  }

  // ---- init: h slots = 0, x slots = x_0 ----
  if (isU) {
    int col = 20 + u;
    zb[(col / 10) * 12 + (col % 10)] = 0.0f;
  }
  if (FIRST) {
    if (lane < 5) raw[lane] = xg[(size_t)n * 5 + lane];
    asm volatile("s_waitcnt lgkmcnt(0)" ::: "memory");
    if (isU) {
      float a = raw[0] * e0 + raw[1] * e1 + raw[2] * e2 + raw[3] * e3 + raw[4] * e4;
      zb[(u / 10) * 12 + (u % 10)] = fmaxf(a, 0.0f);
    }
  } else {
    if (isU) zb[(u / 10) * 12 + (u % 10)] = seq[(size_t)n * 20 + u];
  }
  asm volatile("s_waitcnt lgkmcnt(0)" ::: "memory");

  float c = 0.0f;
  for (int t = 0; t < T_; t++) {
    // prefetch next-step input (20-lane 80B span; consumed at step end)
    float px = 0.0f;
    if (t + 1 < T_) {
      if (FIRST) {
        if (lane < 5) px = xg[(size_t)(t + 1) * (N_ * 5) + n * 5 + lane];
      } else {
        if (isU) px = seq[(size_t)(t + 1) * (N_ * 20) + n * 20 + u];
      }
    }
    // z = [x_t | h_t] slice for this cg (broadcast, conflict-free)
    float z[10];
    {
      const float* zp = zb + cg * 12;
      float4 a4 = *reinterpret_cast<const float4*>(zp);
      float4 b4 = *reinterpret_cast<const float4*>(zp + 4);
      float2 c2 = *reinterpret_cast<const float2*>(zp + 8);
      z[0] = a4.x; z[1] = a4.y; z[2] = a4.z; z[3] = a4.w;
      z[4] = b4.x; z[5] = b4.y; z[6] = b4.z; z[7] = b4.w;
      z[8] = c2.x; z[9] = c2.y;
    }
    float acc[5];
#pragma unroll
    for (int j = 0; j < 5; j++) {
      float a = wr[j][0] * z[0];
#pragma unroll
      for (int m = 1; m < 10; m++) a += wr[j][m] * z[m];
      acc[j] = a;
    }
    // col-combine over cg (lane bits 0-1): quad_perm DPP, VALU pipe
#pragma unroll
    for (int j = 0; j < 5; j++) acc[j] += __shfl_xor(acc[j], 1, 64);
#pragma unroll
    for (int j = 0; j < 5; j++) acc[j] += __shfl_xor(acc[j], 2, 64);
    if (cg == 0) {
#pragma unroll
      for (int j = 0; j < 5; j++) gr[rg * 5 + j] = acc[j];
    }
    asm volatile("s_waitcnt lgkmcnt(0)" ::: "memory");
    // gates / state / IO (lanes u<20)
    if (isU) {
      float gi = gr[u] + bi;
      float gf = gr[20 + u] + bf;
      float gg = gr[40 + u] + bg;
      float go = gr[60 + u] + bo;
      float cu = sigf(gf) * c + sigf(gi) * tanhf_fast(gg);
      c = cu;
      float h = sigf(go) * tanhf_fast(cu);
      seq[(size_t)t * (N_ * 20) + n * 20 + u] = h;   // 80B contiguous per wave
      int col = 20 + u;
      zb[(col / 10) * 12 + (col % 10)] = h;
    }
    if (t + 1 < T_) {
      if (FIRST) {
        if (lane < 5) raw[lane] = px;
        asm volatile("s_waitcnt lgkmcnt(0) vmcnt(0)" ::: "memory");
        if (isU) {
          float a = raw[0] * e0 + raw[1] * e1 + raw[2] * e2 + raw[3] * e3 + raw[4] * e4;
          zb[(u / 10) * 12 + (u % 10)] = fmaxf(a, 0.0f);
        }
      } else {
        if (isU) zb[(u / 10) * 12 + (u % 10)] = px;
      }
    }
    asm volatile("s_waitcnt lgkmcnt(0)" ::: "memory");
  }
}

// ---------------- attention over T, one wave per element ----------------
__global__ void __launch_bounds__(256) attn_kernel(
    const float* __restrict__ seq, const float* __restrict__ w1,
    const float* __restrict__ b1v, const float* __restrict__ w2,
    const float* __restrict__ b2v, float* __restrict__ xh, float* __restrict__ xhn) {
  const int wv = threadIdx.x >> 6;
  const int t = threadIdx.x & 63;
  const int n = (blockIdx.x << 2) + wv;
  const bool act = (t < T_);
  float enc[20];
#pragma unroll
  for (int k = 0; k < 20; k++) enc[k] = 0.0f;
  if (act) {
    const float* p = seq + (t * N_ + n) * H_;
#pragma unroll
    for (int q = 0; q < 5; q++) {
      float4 v = *reinterpret_cast<const float4*>(p + 4 * q);
      enc[4 * q] = v.x; enc[4 * q + 1] = v.y; enc[4 * q + 2] = v.z; enc[4 * q + 3] = v.w;
    }
  }
  float e = -3.0e38f;
  if (act) {
    e = b2v[0];
#pragma unroll 4
    for (int k = 0; k < 64; k++) {
      float s = b1v[k];
      const float* wr = w1 + k * 20;
#pragma unroll
      for (int m = 0; m < 20; m++) s += wr[m] * enc[m];
      s = fmaxf(s, 0.0f);
      e += w2[k] * s;
    }
  }
  float mx = e;
#pragma unroll
  for (int d = 32; d; d >>= 1) mx = fmaxf(mx, __shfl_xor(mx, d, 64));
  float p_ = act ? __expf(e - mx) : 0.0f;
  float sm = p_;
#pragma unroll
  for (int d = 32; d; d >>= 1) sm += __shfl_xor(sm, d, 64);
  float w = __fdividef(p_, sm);
  float a[20];
#pragma unroll
  for (int k = 0; k < 20; k++) a[k] = enc[k] * w;
#pragma unroll
  for (int d = 1; d < 64; d <<= 1) {
#pragma unroll
    for (int k = 0; k < 20; k++) a[k] += __shfl_xor(a[k], d, 64);
  }
  if (t == 0) {
    float* op = xh + n * 20;
    float s2 = 0.0f;
#pragma unroll
    for (int k = 0; k < 20; k++) s2 += a[k] * a[k];
#pragma unroll
    for (int q = 0; q < 5; q++) {
      float4 v; v.x = a[4 * q]; v.y = a[4 * q + 1]; v.z = a[4 * q + 2]; v.w = a[4 * q + 3];
      *reinterpret_cast<float4*>(op + 4 * q) = v;
    }
    xhn[n] = sqrtf(s2);
  }
}

// ---------------- x0 norms ----------------
__global__ void __launch_bounds__(256) x0norm_kernel(const float* __restrict__ x0,
                                                     float* __restrict__ nx0,
                                                     float* __restrict__ rx0) {
  int j = blockIdx.x * 256 + threadIdx.x;
  if (j >= N0_) return;
  float s = 0.f;
#pragma unroll
  for (int k = 0; k < 20; k++) { float v = x0[j * 20 + k]; s += v * v; }
  float nv = sqrtf(s);
  nx0[j] = nv;
  rx0[j] = 1.0f / nv;
}

// ---------------- top-6 cosine, 4 lanes per row ----------------
__device__ __forceinline__ bool better_(float v1, int i1, float v2, int i2) {
  return (v1 > v2) || (v1 == v2 && i1 < i2);
}

__device__ __forceinline__ void merge6(float tv[6], int ti[6], int d) {
  float cv[12]; int ci[12];
#pragma unroll
  for (int z = 0; z < 6; z++) { cv[z] = tv[z]; ci[z] = ti[z]; }
#pragma unroll
  for (int z = 0; z < 6; z++) {
    cv[6 + z] = __shfl_xor(tv[z], d, 64);
    ci[6 + z] = __shfl_xor(ti[z], d, 64);
  }
#pragma unroll
  for (int o = 0; o < 6; o++) {
    float bv = -3.0e38f; int bi = 0x7fffffff; int bm = -1;
#pragma unroll
    for (int m = 0; m < 12; m++) {
      bool bt = better_(cv[m], ci[m], bv, bi);
      if (bt) { bv = cv[m]; bi = ci[m]; bm = m; }
    }
    tv[o] = bv; ti[o] = bi;
#pragma unroll
    for (int m = 0; m < 12; m++) if (m == bm) cv[m] = -3.0e38f;
  }
}

__global__ void __launch_bounds__(256) topk_kernel(
    const float* __restrict__ x0, const float* __restrict__ xh,
    const float* __restrict__ xhn, const float* __restrict__ nx0,
    const float* __restrict__ rx0, int* __restrict__ top5) {
  const int gt = blockIdx.x * 256 + threadIdx.x;
  const int i = gt >> 2, sub = gt & 3;
  float q[20];
  const float* qp = xh + i * 20;
#pragma unroll
  for (int z = 0; z < 5; z++) {
    float4 v = *reinterpret_cast<const float4*>(qp + 4 * z);
    q[4 * z] = v.x; q[4 * z + 1] = v.y; q[4 * z + 2] = v.z; q[4 * z + 3] = v.w;
  }
  float tv[6]; int ti[6];
#pragma unroll
  for (int z = 0; z < 6; z++) { tv[z] = -1.0e30f; ti[z] = 0x7fffffff; }
  for (int j = sub; j < N0_; j += 4) {
    const float* xr = x0 + j * 20;
    float d0 = 0.f;
#pragma unroll
    for (int k = 0; k < 20; k++) d0 += q[k] * xr[k];
    float key = d0 * rx0[j];
    if (key > tv[5]) {       // within-lane j ascending => strict > keeps stability
      tv[5] = key; ti[5] = j;
#pragma unroll
      for (int z = 5; z >= 1; z--) {
        bool sw = better_(tv[z], ti[z], tv[z - 1], ti[z - 1]);
        if (sw) {
          float fv = tv[z]; tv[z] = tv[z - 1]; tv[z - 1] = fv;
          int iv = ti[z]; ti[z] = ti[z - 1]; ti[z - 1] = iv;
        }
      }
    }
  }
  merge6(tv, ti, 1);
  merge6(tv, ti, 2);
  if (sub == 0) {
    const float* xr = x0 + ti[0] * 20;
    float d0 = 0.f;
#pragma unroll
    for (int k = 0; k < 20; k++) d0 += q[k] * xr[k];
    float a = (d0 / xhn[i]) / nx0[ti[0]];   // replicate ref's exact-match branch
    int base = (a == 1.0f) ? 1 : 0;
#pragma unroll
    for (int z = 0; z < 5; z++) top5[i * 5 + z] = ti[base + z];
  }
}

// ---------------- SAGE layer-1 aggregation over edge_0 ----------------
__global__ void __launch_bounds__(256) scatter_kernel(const int* __restrict__ edge,
                                                      const float* __restrict__ x0,
                                                      float* sum1, float* cnt1) {
  int e = blockIdx.x * 256 + threadIdx.x;
  if (e >= E0_) return;
  int s = edge[e], d = edge[E0_ + e];
  const float* xr = x0 + s * 20;
  float* dr = sum1 + d * 20;
#pragma unroll
  for (int k = 0; k < 20; k++) atomicAdd(dr + k, xr[k]);
  atomicAdd(cnt1 + d, 1.0f);
}

__global__ void __launch_bounds__(256) base_kernel(
    const float* __restrict__ x0, const float* __restrict__ sum1,
    const float* __restrict__ cnt1, const float* __restrict__ w1l,
    const float* __restrict__ w1r, const float* __restrict__ b1,
    float* __restrict__ obase) {
  int j = blockIdx.x * 256 + threadIdx.x;
  if (j >= N0_) return;
  float cm = fmaxf(cnt1[j], 1.0f);
  float mean[20], xv[20];
#pragma unroll
  for (int k = 0; k < 20; k++) {
    mean[k] = sum1[j * 20 + k] / cm;
    xv[k] = x0[j * 20 + k];
  }
#pragma unroll
  for (int c = 0; c < HC_; c++) {
    float a = b1[c];
#pragma unroll
    for (int k = 0; k < 20; k++) a += mean[k] * w1l[c * 20 + k];
#pragma unroll
    for (int k = 0; k < 20; k++) a += xv[k] * w1r[c * 20 + k];
    obase[j * HC_ + c] = fmaxf(a, 0.0f);
  }
}

// ---------------- SAGE layer-2 at new nodes + linear + softmax ----------------
__global__ void __launch_bounds__(256) final_kernel(
    const float* __restrict__ xh, const int* __restrict__ top5,
    const float* __restrict__ obase, const float* __restrict__ w1r,
    const float* __restrict__ b1, const float* __restrict__ w2l,
    const float* __restrict__ w2r, const float* __restrict__ b2,
    const float* __restrict__ wlin, const float* __restrict__ blin,
    float* __restrict__ out) {
  int n = blockIdx.x * 256 + threadIdx.x;
  if (n >= N_) return;
  float xq[20];
#pragma unroll
  for (int k = 0; k < 20; k++) xq[k] = xh[n * 20 + k];
  float onw[15];   // layer-1 output at this new node (mean = 0: no incoming edge_0)
#pragma unroll
  for (int c = 0; c < HC_; c++) {
    float a = b1[c];
#pragma unroll
    for (int k = 0; k < 20; k++) a += xq[k] * w1r[c * 20 + k];
    onw[c] = fmaxf(a, 0.0f);
  }
  float mean[15];
#pragma unroll
  for (int c = 0; c < HC_; c++) mean[c] = 0.0f;
#pragma unroll
  for (int z = 0; z < K_; z++) {
    int idx = top5[n * 5 + z];
#pragma unroll
    for (int c = 0; c < HC_; c++) mean[c] += obase[idx * HC_ + c];
  }
#pragma unroll
  for (int c = 0; c < HC_; c++) mean[c] = mean[c] / 5.0f;
  float lg[3];
#pragma unroll
  for (int cl = 0; cl < 3; cl++) lg[cl] = blin[cl];
#pragma unroll
  for (int dd = 0; dd < 20; dd++) {
    float v = b2[dd];
#pragma unroll
    for (int c = 0; c < HC_; c++) v += mean[c] * w2l[dd * HC_ + c] + onw[c] * w2r[dd * HC_ + c];
#pragma unroll
    for (int cl = 0; cl < 3; cl++) lg[cl] += v * wlin[cl * 20 + dd];
  }
  float m = fmaxf(lg[0], fmaxf(lg[1], lg[2]));
  float e0 = expf(lg[0] - m), e1 = expf(lg[1] - m), e2 = expf(lg[2] - m);
  float s = e0 + e1 + e2;
  out[n * 3 + 0] = e0 / s;
  out[n * 3 + 1] = e1 / s;
  out[n * 3 + 2] = e2 / s;
}

extern "C" void kernel_launch(void* const* d_in, const int* in_sizes, int n_in,
                              void* d_out, int out_size, void* d_ws, size_t ws_size,
                              hipStream_t stream) {
  const float* x    = (const float*)d_in[0];
  const float* x0   = (const float*)d_in[1];
  const float* embw = (const float*)d_in[2];
  const float* Wih  = (const float*)d_in[3];
  const float* Whh  = (const float*)d_in[4];
  const float* bih  = (const float*)d_in[5];
  const float* bhh  = (const float*)d_in[6];
  const float* aw1  = (const float*)d_in[7];
  const float* ab1  = (const float*)d_in[8];
  const float* aw2  = (const float*)d_in[9];
  const float* ab2  = (const float*)d_in[10];
  const float* w1l  = (const float*)d_in[11];
  const float* w1r  = (const float*)d_in[12];
  const float* b1   = (const float*)d_in[13];
  const float* w2l  = (const float*)d_in[14];
  const float* w2r  = (const float*)d_in[15];
  const float* b2   = (const float*)d_in[16];
  const float* wlin = (const float*)d_in[17];
  const float* blin = (const float*)d_in[18];
  const int* edge0  = (const int*)d_in[19];

  float* ws    = (float*)d_ws;
  float* seq   = ws + OFF_SEQ;
  float* xh    = ws + OFF_XH;
  float* xhn   = ws + OFF_XHN;
  float* nx0   = ws + OFF_NX0;
  float* rx0   = ws + OFF_RX0;
  int*   top5  = (int*)(ws + OFF_TOP5);
  float* sum1  = ws + OFF_SUM1;
  float* cnt1  = ws + OFF_CNT1;
  float* obase = ws + OFF_OBASE;
  float* out   = (float*)d_out;

  hipMemsetAsync(sum1, 0, (size_t)(N0_ * H_ + N0_) * sizeof(float), stream);
  lstm_wpe_kernel<true><<<N_ / 4, 256, 0, stream>>>(x, embw, Wih, Whh, bih, bhh, seq);
  for (int l = 1; l < 4; l++)
    lstm_wpe_kernel<false><<<N_ / 4, 256, 0, stream>>>(x, embw, Wih + l * 1600,
                                                       Whh + l * 1600, bih + l * 80,
                                                       bhh + l * 80, seq);
  attn_kernel<<<N_ / 4, 256, 0, stream>>>(seq, aw1, ab1, aw2, ab2, xh, xhn);
  x0norm_kernel<<<(N0_ + 255) / 256, 256, 0, stream>>>(x0, nx0, rx0);
  topk_kernel<<<(N_ * 4) / 256, 256, 0, stream>>>(x0, xh, xhn, nx0, rx0, top5);
  scatter_kernel<<<(E0_ + 255) / 256, 256, 0, stream>>>(edge0, x0, sum1, cnt1);
  base_kernel<<<(N0_ + 255) / 256, 256, 0, stream>>>(x0, sum1, cnt1, w1l, w1r, b1, obase);
  final_kernel<<<N_ / 256, 256, 0, stream>>>(xh, top5, obase, w1r, b1, w2l, w2r, b2,
                                             wlin, blin, out);
}